// Round 1
// baseline (5020.008 us; speedup 1.0000x reference)
//
#include <hip/hip_runtime.h>
#include <hip/hip_bf16.h>

// Sizes (fixed per problem)
#define Bz 64
#define Sz 256
#define Ez 256
#define Hz 256
#define Lz 1024
#define VLz 16

// ---------------------------------------------------------------------------
// K1: Vsum[l,e] = sum_j emb[V_idx[l,j], e]; also vnorm[l] = ||Vsum[l]||
__global__ void vsum_kernel(const int* __restrict__ V_idx, const float* __restrict__ emb,
                            float* __restrict__ Vsum, float* __restrict__ vnorm)
{
    int l = blockIdx.x, e = threadIdx.x;
    float s = 0.f;
#pragma unroll
    for (int j = 0; j < VLz; ++j) {
        int idx = V_idx[l * VLz + j];
        s += emb[(long)idx * Ez + e];
    }
    Vsum[l * Ez + e] = s;
    __shared__ float red[256];
    red[e] = s * s; __syncthreads();
    for (int off = 128; off > 0; off >>= 1) { if (e < off) red[e] += red[e + off]; __syncthreads(); }
    if (e == 0) vnorm[l] = sqrtf(red[0]);
}

// K2: xe gather
__global__ void xe_kernel(const int* __restrict__ x, const float* __restrict__ emb,
                          float* __restrict__ xe)
{
    int i = blockIdx.x;              // b*S+s
    int e = threadIdx.x;
    xe[(long)i * Ez + e] = emb[(long)x[i] * Ez + e];
}

// K3: transpose w_hh [768,256] -> wT [256,768] for both directions
__global__ void wt_kernel(const float* __restrict__ w_f, const float* __restrict__ w_b,
                          float* __restrict__ wT_f, float* __restrict__ wT_b)
{
    int i = blockIdx.x * 256 + threadIdx.x;   // over 768*256
    int g = i / 256, k = i % 256;
    wT_f[k * 768 + g] = w_f[i];
    wT_b[k * 768 + g] = w_b[i];
}

// ---------------------------------------------------------------------------
// Generic tiled fp32 GEMM.  C[m,n] = sum_k A[m,k] * B(n,k or k,n) (+bias[n]) (+epilogue)
// TRANS_B=1: B row-major [N,K] (C = A*B^T).  TRANS_B=0: B row-major [K,N].
// EPI: 0 none, 1 relu, 2 tanh.  BIAS: 0/1.
template<int TRANS_B, int EPI, int BIAS>
__global__ __launch_bounds__(256) void gemm_tiled(
    const float* __restrict__ A, const float* __restrict__ Bm,
    const float* __restrict__ bias, float* __restrict__ C,
    int M, int N, int K, long strideA, long strideB, long strideC)
{
    int bz = blockIdx.z;
    A += (long)bz * strideA; Bm += (long)bz * strideB; C += (long)bz * strideC;
    __shared__ float As[16][65];
    __shared__ float Bs[16][65];
    int tid = threadIdx.x;
    int tm = tid >> 4, tn = tid & 15;
    int m0 = blockIdx.y * 64, n0 = blockIdx.x * 64;
    float acc[4][4] = {};
    for (int k0 = 0; k0 < K; k0 += 16) {
#pragma unroll
        for (int i = tid; i < 64 * 16; i += 256) {
            int m = i >> 4, k = i & 15;
            As[k][m] = A[(long)(m0 + m) * K + k0 + k];
        }
        if (TRANS_B) {
#pragma unroll
            for (int i = tid; i < 64 * 16; i += 256) {
                int n = i >> 4, k = i & 15;
                Bs[k][n] = Bm[(long)(n0 + n) * K + k0 + k];
            }
        } else {
#pragma unroll
            for (int i = tid; i < 64 * 16; i += 256) {
                int k = i >> 6, n = i & 63;
                Bs[k][n] = Bm[(long)(k0 + k) * N + n0 + n];
            }
        }
        __syncthreads();
#pragma unroll
        for (int k = 0; k < 16; ++k) {
            float a[4], b[4];
#pragma unroll
            for (int i = 0; i < 4; ++i) a[i] = As[k][tm * 4 + i];
#pragma unroll
            for (int j = 0; j < 4; ++j) b[j] = Bs[k][tn * 4 + j];
#pragma unroll
            for (int i = 0; i < 4; ++i)
#pragma unroll
                for (int j = 0; j < 4; ++j) acc[i][j] += a[i] * b[j];
        }
        __syncthreads();
    }
#pragma unroll
    for (int i = 0; i < 4; ++i) {
        int m = m0 + tm * 4 + i;
#pragma unroll
        for (int j = 0; j < 4; ++j) {
            int n = n0 + tn * 4 + j;
            float v = acc[i][j];
            if (BIAS) v += bias[n];
            if (EPI == 1) v = fmaxf(v, 0.f);
            if (EPI == 2) v = tanhf(v);
            C[(long)m * N + n] = v;
        }
    }
}

// ---------------------------------------------------------------------------
// K4: GRU recurrence, one block per (dir, batch). h kept in LDS.
__global__ __launch_bounds__(256) void gru_kernel(
    const float* __restrict__ gx_f, const float* __restrict__ gx_b,
    const float* __restrict__ wT_f, const float* __restrict__ wT_b,
    const float* __restrict__ bhh_f, const float* __restrict__ bhh_b,
    float* __restrict__ d)
{
    int dir = blockIdx.x >> 6;
    int b   = blockIdx.x & 63;
    const float* gx  = dir ? gx_b : gx_f;
    const float* wT  = dir ? wT_b : wT_f;
    const float* bhh = dir ? bhh_b : bhh_f;
    int t = threadIdx.x;
    __shared__ float h[256];
    h[t] = 0.f;
    float br = bhh[t], bz2 = bhh[256 + t], bn2 = bhh[512 + t];
    __syncthreads();
    for (int step = 0; step < Sz; ++step) {
        int s = dir ? (Sz - 1 - step) : step;
        float ar = br, az = bz2, an = bn2;
        const float* g = gx + (long)(b * Sz + s) * 768;
#pragma unroll 4
        for (int k = 0; k < 256; ++k) {
            float hk = h[k];
            const float* w = wT + k * 768;
            ar += w[t] * hk;
            az += w[256 + t] * hk;
            an += w[512 + t] * hk;
        }
        float r = 1.f / (1.f + expf(-(g[t] + ar)));
        float z = 1.f / (1.f + expf(-(g[256 + t] + az)));
        float n = tanhf(g[512 + t] + r * an);
        float hv = h[t];
        float hnew = (1.f - z) * n + z * hv;
        __syncthreads();
        h[t] = hnew;
        d[(long)(b * Sz + s) * 512 + dir * 256 + t] = hnew;
        __syncthreads();
    }
}

// ---------------------------------------------------------------------------
// BN stats over (b, e) for each channel c (layout y[b][CH][256])
__global__ void bn_stats_kernel(const float* __restrict__ y, int CH,
                                float* __restrict__ mean, float* __restrict__ istd)
{
    int c = blockIdx.x, t = threadIdx.x;
    float s = 0.f, ss = 0.f;
    for (int b = 0; b < Bz; ++b) {
        float v = y[((long)b * CH + c) * 256 + t];
        s += v; ss += v * v;
    }
    __shared__ float rs[256], rss[256];
    rs[t] = s; rss[t] = ss; __syncthreads();
    for (int off = 128; off > 0; off >>= 1) {
        if (t < off) { rs[t] += rs[t + off]; rss[t] += rss[t + off]; }
        __syncthreads();
    }
    if (t == 0) {
        float cnt = (float)(Bz * 256);
        float m = rs[0] / cnt;
        float var = rss[0] / cnt - m * m;
        mean[c] = m;
        istd[c] = rsqrtf(var + 1e-5f);
    }
}

// BN apply + activation, in place.  EPI: 1 relu, 2 tanh
template<int EPI>
__global__ void bn_apply_kernel(float* __restrict__ y, int CH,
                                const float* __restrict__ mean, const float* __restrict__ istd,
                                const float* __restrict__ g, const float* __restrict__ be)
{
    long i = (long)blockIdx.x * 256 + threadIdx.x;  // over B*CH*256
    int c = (int)((i >> 8) % CH);
    float v = (y[i] - mean[c]) * istd[c] * g[c] + be[c];
    y[i] = (EPI == 1) ? fmaxf(v, 0.f) : tanhf(v);
}

// ---------------------------------------------------------------------------
// Output: cosine similarity * 10
__global__ void out_kernel(const float* __restrict__ e, const float* __restrict__ Vsum,
                           const float* __restrict__ vnorm, float* __restrict__ out)
{
    int bl = blockIdx.x;
    int l = bl & (Lz - 1);
    int t = threadIdx.x;
    float ev = e[(long)bl * 256 + t];
    float vv = Vsum[l * 256 + t];
    __shared__ float rd[256], rn[256];
    rd[t] = ev * vv; rn[t] = ev * ev; __syncthreads();
    for (int off = 128; off > 0; off >>= 1) {
        if (t < off) { rd[t] += rd[t + off]; rn[t] += rn[t + off]; }
        __syncthreads();
    }
    if (t == 0) {
        float num = rd[0];
        float den = fmaxf(sqrtf(rn[0]), 1e-8f) * fmaxf(vnorm[l], 1e-8f);
        out[bl] = num / den * 10.f;
    }
}

// ---------------------------------------------------------------------------
extern "C" void kernel_launch(void* const* d_in, const int* in_sizes, int n_in,
                              void* d_out, int out_size, void* d_ws, size_t ws_size,
                              hipStream_t stream)
{
    const int*   x      = (const int*)d_in[0];
    const int*   V_idx  = (const int*)d_in[1];
    const float* emb    = (const float*)d_in[2];
    const float* w_ih_f = (const float*)d_in[3];
    const float* w_hh_f = (const float*)d_in[4];
    const float* b_ih_f = (const float*)d_in[5];
    const float* b_hh_f = (const float*)d_in[6];
    const float* w_ih_b = (const float*)d_in[7];
    const float* w_hh_b = (const float*)d_in[8];
    const float* b_ih_b = (const float*)d_in[9];
    const float* b_hh_b = (const float*)d_in[10];
    const float* w1     = (const float*)d_in[11];
    const float* b1     = (const float*)d_in[12];
    const float* w2     = (const float*)d_in[13];
    const float* b2     = (const float*)d_in[14];
    const float* g1     = (const float*)d_in[15];
    const float* be1    = (const float*)d_in[16];
    const float* g2     = (const float*)d_in[17];
    const float* be2    = (const float*)d_in[18];

    float* ws = (float*)d_ws;
    float* out = (float*)d_out;

    // workspace layout (floats)
    size_t o_vsum  = 0;                       // 262144
    size_t o_vnorm = o_vsum + 262144;         // 1024
    size_t o_mean  = o_vnorm + 1024;          // 1024
    size_t o_istd  = o_mean + 1024;           // 1024
    size_t o_wTf   = o_istd + 1024;           // 196608
    size_t o_wTb   = o_wTf + 196608;          // 196608
    size_t o_d     = o_wTb + 196608;          // 8388608  d [B,S,512]
    size_t o_pool  = o_d + 8388608;
    // pool: xe(4.19M) | gx_f(12.58M) | gx_b(12.58M) during stages 1-3
    //        d2(4.19M) | a(16.77M)   | c(33.55M)    during stages 4-6
    //        epre(16.77M) spanning d2+a after they are dead
    float* vsum  = ws + o_vsum;
    float* vnorm = ws + o_vnorm;
    float* mean  = ws + o_mean;
    float* istd  = ws + o_istd;
    float* wTf   = ws + o_wTf;
    float* wTb   = ws + o_wTb;
    float* dbuf  = ws + o_d;
    float* xe    = ws + o_pool;
    float* gxf   = ws + o_pool + 4194304;
    float* gxb   = ws + o_pool + 4194304 + 12582912;
    float* d2    = ws + o_pool;                       // after xe dead
    float* abuf  = ws + o_pool + 4194304;             // after gx dead
    float* cbuf  = ws + o_pool + 4194304 + 16777216;  // fresh
    float* epre  = ws + o_pool;                       // after d2+a dead

    // Stage 1: gathers
    vsum_kernel<<<Lz, 256, 0, stream>>>(V_idx, emb, vsum, vnorm);
    xe_kernel<<<Bz * Sz, 256, 0, stream>>>(x, emb, xe);
    wt_kernel<<<768, 256, 0, stream>>>(w_hh_f, w_hh_b, wTf, wTb);

    // Stage 2: gx = xe @ w_ih^T + b_ih  (M=16384, N=768, K=256)
    gemm_tiled<1, 0, 1><<<dim3(12, 256, 1), 256, 0, stream>>>(
        xe, w_ih_f, b_ih_f, gxf, Bz * Sz, 768, Ez, 0, 0, 0);
    gemm_tiled<1, 0, 1><<<dim3(12, 256, 1), 256, 0, stream>>>(
        xe, w_ih_b, b_ih_b, gxb, Bz * Sz, 768, Ez, 0, 0, 0);

    // Stage 3: GRU recurrence -> dbuf [B,S,512]
    gru_kernel<<<128, 256, 0, stream>>>(gxf, gxb, wTf, wTb, b_hh_f, b_hh_b, dbuf);

    // Stage 4: d2pre = d @ w1^T + b1  (M=16384, N=256, K=512), then BN1+relu
    gemm_tiled<1, 0, 1><<<dim3(4, 256, 1), 256, 0, stream>>>(
        dbuf, w1, b1, d2, Bz * Sz, Ez, 512, 0, 0, 0);
    bn_stats_kernel<<<Sz, 256, 0, stream>>>(d2, Sz, mean, istd);
    bn_apply_kernel<1><<<Bz * Sz, 256, 0, stream>>>(d2, Sz, mean, istd, g1, be1);

    // Stage 5: a[b] = tanh(Vsum @ d2[b]^T)   (M=1024, N=256, K=256, batched over b)
    gemm_tiled<1, 2, 0><<<dim3(4, 16, Bz), 256, 0, stream>>>(
        vsum, d2, nullptr, abuf, Lz, Sz, Ez, 0, (long)Sz * Ez, (long)Lz * Sz);

    // Stage 6: c[b] = relu(a[b] @ d[b])      (M=1024, N=512, K=256, batched over b)
    gemm_tiled<0, 1, 0><<<dim3(8, 16, Bz), 256, 0, stream>>>(
        abuf, dbuf, nullptr, cbuf, Lz, 512, Sz, (long)Lz * Sz, (long)Sz * 512, (long)Lz * 512);

    // Stage 7: epre = c @ w2^T + b2  (M=65536, N=256, K=512), then BN2+tanh
    gemm_tiled<1, 0, 1><<<dim3(4, 1024, 1), 256, 0, stream>>>(
        cbuf, w2, b2, epre, Bz * Lz, Ez, 512, 0, 0, 0);
    bn_stats_kernel<<<Lz, 256, 0, stream>>>(epre, Lz, mean, istd);
    bn_apply_kernel<2><<<Bz * Lz, 256, 0, stream>>>(epre, Lz, mean, istd, g2, be2);

    // Stage 8: output
    out_kernel<<<Bz * Lz, 256, 0, stream>>>(epre, vsum, vnorm, out);
}

// Round 2
// 1827.883 us; speedup vs baseline: 2.7464x; 2.7464x over previous
//
#include <hip/hip_runtime.h>
#include <hip/hip_bf16.h>

// Sizes (fixed per problem)
#define Bz 64
#define Sz 256
#define Ez 256
#define Hz 256
#define Lz 1024
#define VLz 16

typedef _Float16 half2_t __attribute__((ext_vector_type(2)));
typedef _Float16 half4_t __attribute__((ext_vector_type(4)));

__device__ inline float fdot2(half2_t a, half2_t b, float c) {
#if __has_builtin(__builtin_amdgcn_fdot2)
    return __builtin_amdgcn_fdot2(a, b, c, false);
#else
    return c + (float)a[0] * (float)b[0] + (float)a[1] * (float)b[1];
#endif
}

// ---------------------------------------------------------------------------
// K1: Vsum[l,e] = sum_j emb[V_idx[l,j], e]; also vnorm[l] = ||Vsum[l]||
__global__ void vsum_kernel(const int* __restrict__ V_idx, const float* __restrict__ emb,
                            float* __restrict__ Vsum, float* __restrict__ vnorm)
{
    int l = blockIdx.x, e = threadIdx.x;
    float s = 0.f;
#pragma unroll
    for (int j = 0; j < VLz; ++j) {
        int idx = V_idx[l * VLz + j];
        s += emb[(long)idx * Ez + e];
    }
    Vsum[l * Ez + e] = s;
    __shared__ float red[256];
    red[e] = s * s; __syncthreads();
    for (int off = 128; off > 0; off >>= 1) { if (e < off) red[e] += red[e + off]; __syncthreads(); }
    if (e == 0) vnorm[l] = sqrtf(red[0]);
}

// K2: xe gather
__global__ void xe_kernel(const int* __restrict__ x, const float* __restrict__ emb,
                          float* __restrict__ xe)
{
    int i = blockIdx.x;              // b*S+s
    int e = threadIdx.x;
    xe[(long)i * Ez + e] = emb[(long)x[i] * Ez + e];
}

// K3: pack w_hh [768,256] fp32 -> f16x2 quad layout for the GRU.
// out index i = ((kq*3+g)*2+p)*256 + t  holds (w[g*256+t][4kq+2p], w[g*256+t][4kq+2p+1])
__global__ void wpack_kernel(const float* __restrict__ w_f, const float* __restrict__ w_b,
                             half2_t* __restrict__ out_f, half2_t* __restrict__ out_b)
{
    int i = blockIdx.x * 256 + threadIdx.x;   // 0 .. 98303
    int t = i & 255;
    int rest = i >> 8;          // (kq*3+g)*2+p
    int p = rest & 1;
    int gq = rest >> 1;
    int g = gq % 3;
    int kq = gq / 3;
    int o = g * 256 + t;        // output row of w_hh
    int k = 4 * kq + 2 * p;
    out_f[i] = half2_t{(_Float16)w_f[o * 256 + k], (_Float16)w_f[o * 256 + k + 1]};
    out_b[i] = half2_t{(_Float16)w_b[o * 256 + k], (_Float16)w_b[o * 256 + k + 1]};
}

// ---------------------------------------------------------------------------
// Generic tiled fp32 GEMM.  C[m,n] = sum_k A[m,k] * B(n,k or k,n) (+bias[n]) (+epilogue)
// TRANS_B=1: B row-major [N,K] (C = A*B^T).  TRANS_B=0: B row-major [K,N].
// EPI: 0 none, 1 relu, 2 tanh.  BIAS: 0/1.
template<int TRANS_B, int EPI, int BIAS>
__global__ __launch_bounds__(256) void gemm_tiled(
    const float* __restrict__ A, const float* __restrict__ Bm,
    const float* __restrict__ bias, float* __restrict__ C,
    int M, int N, int K, long strideA, long strideB, long strideC)
{
    int bz = blockIdx.z;
    A += (long)bz * strideA; Bm += (long)bz * strideB; C += (long)bz * strideC;
    __shared__ float As[16][65];
    __shared__ float Bs[16][65];
    int tid = threadIdx.x;
    int tm = tid >> 4, tn = tid & 15;
    int m0 = blockIdx.y * 64, n0 = blockIdx.x * 64;
    float acc[4][4] = {};
    for (int k0 = 0; k0 < K; k0 += 16) {
#pragma unroll
        for (int i = tid; i < 64 * 16; i += 256) {
            int m = i >> 4, k = i & 15;
            As[k][m] = A[(long)(m0 + m) * K + k0 + k];
        }
        if (TRANS_B) {
#pragma unroll
            for (int i = tid; i < 64 * 16; i += 256) {
                int n = i >> 4, k = i & 15;
                Bs[k][n] = Bm[(long)(n0 + n) * K + k0 + k];
            }
        } else {
#pragma unroll
            for (int i = tid; i < 64 * 16; i += 256) {
                int k = i >> 6, n = i & 63;
                Bs[k][n] = Bm[(long)(k0 + k) * N + n0 + n];
            }
        }
        __syncthreads();
#pragma unroll
        for (int k = 0; k < 16; ++k) {
            float a[4], b[4];
#pragma unroll
            for (int i = 0; i < 4; ++i) a[i] = As[k][tm * 4 + i];
#pragma unroll
            for (int j = 0; j < 4; ++j) b[j] = Bs[k][tn * 4 + j];
#pragma unroll
            for (int i = 0; i < 4; ++i)
#pragma unroll
                for (int j = 0; j < 4; ++j) acc[i][j] += a[i] * b[j];
        }
        __syncthreads();
    }
#pragma unroll
    for (int i = 0; i < 4; ++i) {
        int m = m0 + tm * 4 + i;
#pragma unroll
        for (int j = 0; j < 4; ++j) {
            int n = n0 + tn * 4 + j;
            float v = acc[i][j];
            if (BIAS) v += bias[n];
            if (EPI == 1) v = fmaxf(v, 0.f);
            if (EPI == 2) v = tanhf(v);
            C[(long)m * N + n] = v;
        }
    }
}

// ---------------------------------------------------------------------------
// K4: GRU recurrence. One block per (dir, batch), 1024 threads = 16 waves.
// Weights live in registers (96 f16x2 dwords/thread). h shared via LDS (f16).
// Thread (q,t): q = k-chunk (64 k's), t = output index within H.
__global__ __launch_bounds__(1024) void gru_kernel(
    const float* __restrict__ gx_f, const float* __restrict__ gx_b,
    const half2_t* __restrict__ wq_f, const half2_t* __restrict__ wq_b,
    const float* __restrict__ bhh_f, const float* __restrict__ bhh_b,
    float* __restrict__ d)
{
    int dir = blockIdx.x >> 6;
    int b   = blockIdx.x & 63;
    const float*   gx  = dir ? gx_b : gx_f;
    const half2_t* wq  = dir ? wq_b : wq_f;
    const float*   bhh = dir ? bhh_b : bhh_f;
    int tid = threadIdx.x;
    int t = tid & 255, q = tid >> 8;

    __shared__ __attribute__((aligned(16))) _Float16 hbuf[256];
    __shared__ float part[4 * 768];

    // one-time: weights -> registers (static indices only)
    half2_t wr[96];
    const half2_t* wbase = wq + (size_t)q * 96 * 256 + t;
#pragma unroll
    for (int m = 0; m < 96; ++m) wr[m] = wbase[m << 8];

    float br = 0.f, bz = 0.f, bn = 0.f, hprev = 0.f;
    if (q == 0) {
        br = bhh[t]; bz = bhh[256 + t]; bn = bhh[512 + t];
        hbuf[t] = (_Float16)0.f;
    }
    __syncthreads();

    for (int step = 0; step < Sz; ++step) {
        int s = dir ? (Sz - 1 - step) : step;
        const float* g = gx + (size_t)(b * Sz + s) * 768;
        float xr = 0.f, xz = 0.f, xn = 0.f;
        if (q == 0) { xr = g[t]; xz = g[256 + t]; xn = g[512 + t]; }

        float ar = 0.f, az = 0.f, an = 0.f;
        const half4_t* hp = (const half4_t*)hbuf;
#pragma unroll
        for (int jj = 0; jj < 16; ++jj) {
            half4_t hv = hp[q * 16 + jj];
            half2_t h01 = {hv[0], hv[1]};
            half2_t h23 = {hv[2], hv[3]};
            ar = fdot2(wr[jj * 6 + 0], h01, ar); ar = fdot2(wr[jj * 6 + 1], h23, ar);
            az = fdot2(wr[jj * 6 + 2], h01, az); az = fdot2(wr[jj * 6 + 3], h23, az);
            an = fdot2(wr[jj * 6 + 4], h01, an); an = fdot2(wr[jj * 6 + 5], h23, an);
        }
        part[q * 768 + t]       = ar;
        part[q * 768 + 256 + t] = az;
        part[q * 768 + 512 + t] = an;
        __syncthreads();

        if (q == 0) {
            float hr = part[t]       + part[768 + t]       + part[1536 + t]       + part[2304 + t];
            float hz = part[256 + t] + part[768 + 256 + t] + part[1536 + 256 + t] + part[2304 + 256 + t];
            float hn = part[512 + t] + part[768 + 512 + t] + part[1536 + 512 + t] + part[2304 + 512 + t];
            float r  = 1.f / (1.f + expf(-(xr + br + hr)));
            float z  = 1.f / (1.f + expf(-(xz + bz + hz)));
            float nn = tanhf(xn + r * (hn + bn));
            hprev = (1.f - z) * nn + z * hprev;
            d[(size_t)(b * Sz + s) * 512 + dir * 256 + t] = hprev;
            hbuf[t] = (_Float16)hprev;
        }
        __syncthreads();
    }
}

// ---------------------------------------------------------------------------
// BN stats over (b, e) for each channel c (layout y[b][CH][256])
__global__ void bn_stats_kernel(const float* __restrict__ y, int CH,
                                float* __restrict__ mean, float* __restrict__ istd)
{
    int c = blockIdx.x, t = threadIdx.x;
    float s = 0.f, ss = 0.f;
    for (int b = 0; b < Bz; ++b) {
        float v = y[((long)b * CH + c) * 256 + t];
        s += v; ss += v * v;
    }
    __shared__ float rs[256], rss[256];
    rs[t] = s; rss[t] = ss; __syncthreads();
    for (int off = 128; off > 0; off >>= 1) {
        if (t < off) { rs[t] += rs[t + off]; rss[t] += rss[t + off]; }
        __syncthreads();
    }
    if (t == 0) {
        float cnt = (float)(Bz * 256);
        float m = rs[0] / cnt;
        float var = rss[0] / cnt - m * m;
        mean[c] = m;
        istd[c] = rsqrtf(var + 1e-5f);
    }
}

// BN apply + activation, in place.  EPI: 1 relu, 2 tanh
template<int EPI>
__global__ void bn_apply_kernel(float* __restrict__ y, int CH,
                                const float* __restrict__ mean, const float* __restrict__ istd,
                                const float* __restrict__ g, const float* __restrict__ be)
{
    long i = (long)blockIdx.x * 256 + threadIdx.x;  // over B*CH*256
    int c = (int)((i >> 8) % CH);
    float v = (y[i] - mean[c]) * istd[c] * g[c] + be[c];
    y[i] = (EPI == 1) ? fmaxf(v, 0.f) : tanhf(v);
}

// ---------------------------------------------------------------------------
// Output: cosine similarity * 10
__global__ void out_kernel(const float* __restrict__ e, const float* __restrict__ Vsum,
                           const float* __restrict__ vnorm, float* __restrict__ out)
{
    int bl = blockIdx.x;
    int l = bl & (Lz - 1);
    int t = threadIdx.x;
    float ev = e[(long)bl * 256 + t];
    float vv = Vsum[l * 256 + t];
    __shared__ float rd[256], rn[256];
    rd[t] = ev * vv; rn[t] = ev * ev; __syncthreads();
    for (int off = 128; off > 0; off >>= 1) {
        if (t < off) { rd[t] += rd[t + off]; rn[t] += rn[t + off]; }
        __syncthreads();
    }
    if (t == 0) {
        float num = rd[0];
        float den = fmaxf(sqrtf(rn[0]), 1e-8f) * fmaxf(vnorm[l], 1e-8f);
        out[bl] = num / den * 10.f;
    }
}

// ---------------------------------------------------------------------------
extern "C" void kernel_launch(void* const* d_in, const int* in_sizes, int n_in,
                              void* d_out, int out_size, void* d_ws, size_t ws_size,
                              hipStream_t stream)
{
    const int*   x      = (const int*)d_in[0];
    const int*   V_idx  = (const int*)d_in[1];
    const float* emb    = (const float*)d_in[2];
    const float* w_ih_f = (const float*)d_in[3];
    const float* w_hh_f = (const float*)d_in[4];
    const float* b_ih_f = (const float*)d_in[5];
    const float* b_hh_f = (const float*)d_in[6];
    const float* w_ih_b = (const float*)d_in[7];
    const float* w_hh_b = (const float*)d_in[8];
    const float* b_ih_b = (const float*)d_in[9];
    const float* b_hh_b = (const float*)d_in[10];
    const float* w1     = (const float*)d_in[11];
    const float* b1     = (const float*)d_in[12];
    const float* w2     = (const float*)d_in[13];
    const float* b2     = (const float*)d_in[14];
    const float* g1     = (const float*)d_in[15];
    const float* be1    = (const float*)d_in[16];
    const float* g2     = (const float*)d_in[17];
    const float* be2    = (const float*)d_in[18];

    float* ws = (float*)d_ws;
    float* out = (float*)d_out;

    // workspace layout (floats)
    size_t o_vsum  = 0;                       // 262144
    size_t o_vnorm = o_vsum + 262144;         // 1024
    size_t o_mean  = o_vnorm + 1024;          // 1024
    size_t o_istd  = o_mean + 1024;           // 1024
    size_t o_wqf   = o_istd + 1024;           // 98304 dwords (f16x2)
    size_t o_wqb   = o_wqf + 196608;
    size_t o_d     = o_wqb + 196608;          // 8388608  d [B,S,512]
    size_t o_pool  = o_d + 8388608;
    float* vsum  = ws + o_vsum;
    float* vnorm = ws + o_vnorm;
    float* mean  = ws + o_mean;
    float* istd  = ws + o_istd;
    half2_t* wqf = (half2_t*)(ws + o_wqf);
    half2_t* wqb = (half2_t*)(ws + o_wqb);
    float* dbuf  = ws + o_d;
    float* xe    = ws + o_pool;
    float* gxf   = ws + o_pool + 4194304;
    float* gxb   = ws + o_pool + 4194304 + 12582912;
    float* d2    = ws + o_pool;                       // after xe dead
    float* abuf  = ws + o_pool + 4194304;             // after gx dead
    float* cbuf  = ws + o_pool + 4194304 + 16777216;  // fresh
    float* epre  = ws + o_pool;                       // after d2+a dead

    // Stage 1: gathers + weight pack
    vsum_kernel<<<Lz, 256, 0, stream>>>(V_idx, emb, vsum, vnorm);
    xe_kernel<<<Bz * Sz, 256, 0, stream>>>(x, emb, xe);
    wpack_kernel<<<384, 256, 0, stream>>>(w_hh_f, w_hh_b, wqf, wqb);

    // Stage 2: gx = xe @ w_ih^T + b_ih  (M=16384, N=768, K=256)
    gemm_tiled<1, 0, 1><<<dim3(12, 256, 1), 256, 0, stream>>>(
        xe, w_ih_f, b_ih_f, gxf, Bz * Sz, 768, Ez, 0, 0, 0);
    gemm_tiled<1, 0, 1><<<dim3(12, 256, 1), 256, 0, stream>>>(
        xe, w_ih_b, b_ih_b, gxb, Bz * Sz, 768, Ez, 0, 0, 0);

    // Stage 3: GRU recurrence -> dbuf [B,S,512]
    gru_kernel<<<128, 1024, 0, stream>>>(gxf, gxb, wqf, wqb, b_hh_f, b_hh_b, dbuf);

    // Stage 4: d2pre = d @ w1^T + b1  (M=16384, N=256, K=512), then BN1+relu
    gemm_tiled<1, 0, 1><<<dim3(4, 256, 1), 256, 0, stream>>>(
        dbuf, w1, b1, d2, Bz * Sz, Ez, 512, 0, 0, 0);
    bn_stats_kernel<<<Sz, 256, 0, stream>>>(d2, Sz, mean, istd);
    bn_apply_kernel<1><<<Bz * Sz, 256, 0, stream>>>(d2, Sz, mean, istd, g1, be1);

    // Stage 5: a[b] = tanh(Vsum @ d2[b]^T)   (M=1024, N=256, K=256, batched over b)
    gemm_tiled<1, 2, 0><<<dim3(4, 16, Bz), 256, 0, stream>>>(
        vsum, d2, nullptr, abuf, Lz, Sz, Ez, 0, (long)Sz * Ez, (long)Lz * Sz);

    // Stage 6: c[b] = relu(a[b] @ d[b])      (M=1024, N=512, K=256, batched over b)
    gemm_tiled<0, 1, 0><<<dim3(8, 16, Bz), 256, 0, stream>>>(
        abuf, dbuf, nullptr, cbuf, Lz, 512, Sz, (long)Lz * Sz, (long)Sz * 512, (long)Lz * 512);

    // Stage 7: epre = c @ w2^T + b2  (M=65536, N=256, K=512), then BN2+tanh
    gemm_tiled<1, 0, 1><<<dim3(4, 1024, 1), 256, 0, stream>>>(
        cbuf, w2, b2, epre, Bz * Lz, Ez, 512, 0, 0, 0);
    bn_stats_kernel<<<Lz, 256, 0, stream>>>(epre, Lz, mean, istd);
    bn_apply_kernel<2><<<Bz * Lz, 256, 0, stream>>>(epre, Lz, mean, istd, g2, be2);

    // Stage 8: output
    out_kernel<<<Bz * Lz, 256, 0, stream>>>(epre, vsum, vnorm, out);
}

// Round 4
// 720.043 us; speedup vs baseline: 6.9718x; 2.5386x over previous
//
#include <hip/hip_runtime.h>
#include <hip/hip_bf16.h>

// Sizes (fixed per problem)
#define Bz 64
#define Sz 256
#define Ez 256
#define Hz 256
#define Lz 1024
#define VLz 16

// split-precision scale: x stored as hi+lo of (x*SCL); products carry SCL^2
#define SCL 64.0f
#define DESCL (1.0f / 4096.0f)

typedef _Float16 half2_t __attribute__((ext_vector_type(2)));
typedef _Float16 half4_t __attribute__((ext_vector_type(4)));
typedef _Float16 f16x8   __attribute__((ext_vector_type(8)));
typedef float    f32x4   __attribute__((ext_vector_type(4)));

__device__ inline float fdot2(half2_t a, half2_t b, float c) {
#if __has_builtin(__builtin_amdgcn_fdot2)
    return __builtin_amdgcn_fdot2(a, b, c, false);
#else
    return c + (float)a[0] * (float)b[0] + (float)a[1] * (float)b[1];
#endif
}

// async global->LDS 16B; LDS dest must be linear lane-ordered (m104/m173)
__device__ inline void stage16(_Float16* ldst, const _Float16* gsrc) {
#if __has_builtin(__builtin_amdgcn_global_load_lds)
    __builtin_amdgcn_global_load_lds(
        (const __attribute__((address_space(1))) unsigned int*)gsrc,
        (__attribute__((address_space(3))) unsigned int*)ldst, 16, 0, 0);
#else
    *(f16x8*)ldst = *(const f16x8*)gsrc;
#endif
}

// ---------------------------------------------------------------------------
// K1: Vsum[l,e] = sum_j emb[V_idx[l,j], e]; norms; hi/lo split copy
__global__ void vsum_kernel(const int* __restrict__ V_idx, const float* __restrict__ emb,
                            float* __restrict__ Vsum, _Float16* __restrict__ vsh,
                            _Float16* __restrict__ vsl, float* __restrict__ vnorm)
{
    int l = blockIdx.x, e = threadIdx.x;
    float s = 0.f;
#pragma unroll
    for (int j = 0; j < VLz; ++j) {
        int idx = V_idx[l * VLz + j];
        s += emb[(long)idx * Ez + e];
    }
    Vsum[l * Ez + e] = s;
    float t = s * SCL;
    _Float16 h = (_Float16)t;
    vsh[l * Ez + e] = h;
    vsl[l * Ez + e] = (_Float16)(t - (float)h);
    __shared__ float red[256];
    red[e] = s * s; __syncthreads();
    for (int off = 128; off > 0; off >>= 1) { if (e < off) red[e] += red[e + off]; __syncthreads(); }
    if (e == 0) vnorm[l] = sqrtf(red[0]);
}

// K2: xe gather, hi/lo
__global__ void xe_kernel(const int* __restrict__ x, const float* __restrict__ emb,
                          _Float16* __restrict__ xeh, _Float16* __restrict__ xel)
{
    int i = blockIdx.x;              // b*S+s
    int e = threadIdx.x;
    float v = emb[(long)x[i] * Ez + e] * SCL;
    _Float16 h = (_Float16)v;
    xeh[(long)i * Ez + e] = h;
    xel[(long)i * Ez + e] = (_Float16)(v - (float)h);
}

// K3: pack w_hh [768,256] fp32 -> f16x2 quad layout for the GRU (round-2 proven).
__global__ void wpack_kernel(const float* __restrict__ w_f, const float* __restrict__ w_b,
                             half2_t* __restrict__ out_f, half2_t* __restrict__ out_b)
{
    int i = blockIdx.x * 256 + threadIdx.x;   // 0 .. 98303
    int t = i & 255;
    int rest = i >> 8;          // (kq*3+g)*2+p
    int p = rest & 1;
    int gq = rest >> 1;
    int g = gq % 3;
    int kq = gq / 3;
    int o = g * 256 + t;
    int k = 4 * kq + 2 * p;
    out_f[i] = half2_t{(_Float16)w_f[o * 256 + k], (_Float16)w_f[o * 256 + k + 1]};
    out_b[i] = half2_t{(_Float16)w_b[o * 256 + k], (_Float16)w_b[o * 256 + k + 1]};
}

// f32 -> scaled hi/lo f16
__global__ void cvtsplit_kernel(const float* __restrict__ in, _Float16* __restrict__ hi,
                                _Float16* __restrict__ lo, int n)
{
    int i = blockIdx.x * 256 + threadIdx.x;
    if (i < n) {
        float v = in[i] * SCL;
        _Float16 h = (_Float16)v;
        hi[i] = h;
        lo[i] = (_Float16)(v - (float)h);
    }
}

// ---------------------------------------------------------------------------
// Split-precision MFMA NT GEMM: C = (1/4096)*(Ah+Al)@(Bh+Bl)^T (+bias)(+epi).
// acc = Ah*Bh + Ah*Bl (+ Al*Bh if SPLIT_A). BM=BN=128, BK=32, 4 waves 2x2.
// OUTM: 0 = f32 C, 1 = scaled hi/lo f16 (Ch,Cl), 2 = scaled hi f16 only.
template<int EPI, int BIAS, int OUTM, int SPLIT_A>
__global__ __launch_bounds__(256, 2) void gemm_mfma(
    const _Float16* __restrict__ Ah, const _Float16* __restrict__ Al,
    const _Float16* __restrict__ Bh, const _Float16* __restrict__ Bl,
    const float* __restrict__ bias, float* __restrict__ C,
    _Float16* __restrict__ Ch, _Float16* __restrict__ Cl,
    int M, int N, int K, long sA, long sB, long sC)
{
    int bz = blockIdx.z;
    Ah += (long)bz * sA;
    if (SPLIT_A) Al += (long)bz * sA;
    Bh += (long)bz * sB;
    Bl += (long)bz * sB;
    __shared__ __attribute__((aligned(16))) _Float16 Ash[128 * 32];
    __shared__ __attribute__((aligned(16))) _Float16 Asl[128 * 32];
    __shared__ __attribute__((aligned(16))) _Float16 Bsh[128 * 32];
    __shared__ __attribute__((aligned(16))) _Float16 Bsl[128 * 32];
    int tid = threadIdx.x;
    int lane = tid & 63;
    int wid = tid >> 6;
    int wm = wid >> 1, wn = wid & 1;
    int m0 = blockIdx.y * 128, n0 = blockIdx.x * 128;

    // staging: thread -> (row = tid>>2, slot = tid&3); source chunk XOR-swizzled
    int srow = tid >> 2, sslot = tid & 3;
    int sw0 = sslot ^ ((srow >> 1) & 3);          // invariant under row+64
    long a0 = (long)(m0 + srow) * K + sw0 * 8;
    long a1 = (long)(m0 + 64 + srow) * K + sw0 * 8;
    long b0 = (long)(n0 + srow) * K + sw0 * 8;
    long b1 = (long)(n0 + 64 + srow) * K + sw0 * 8;

    f32x4 acc[4][4] = {};
    int r16 = lane & 15, kg = lane >> 4;

    for (int k0 = 0; k0 < K; k0 += 32) {
        stage16(&Ash[tid * 8],        Ah + a0 + k0);
        stage16(&Ash[2048 + tid * 8], Ah + a1 + k0);
        if (SPLIT_A) {
            stage16(&Asl[tid * 8],        Al + a0 + k0);
            stage16(&Asl[2048 + tid * 8], Al + a1 + k0);
        }
        stage16(&Bsh[tid * 8],        Bh + b0 + k0);
        stage16(&Bsh[2048 + tid * 8], Bh + b1 + k0);
        stage16(&Bsl[tid * 8],        Bl + b0 + k0);
        stage16(&Bsl[2048 + tid * 8], Bl + b1 + k0);
        __syncthreads();
        f16x8 afh[4], afl[4], bfh[4], bfl[4];
#pragma unroll
        for (int mi = 0; mi < 4; ++mi) {
            int r = wm * 64 + mi * 16 + r16;
            int sl = kg ^ ((r >> 1) & 3);
            int off = r * 32 + sl * 8;
            afh[mi] = *(const f16x8*)&Ash[off];
            if (SPLIT_A) afl[mi] = *(const f16x8*)&Asl[off];
        }
#pragma unroll
        for (int ni = 0; ni < 4; ++ni) {
            int n = wn * 64 + ni * 16 + r16;
            int sl = kg ^ ((n >> 1) & 3);
            int off = n * 32 + sl * 8;
            bfh[ni] = *(const f16x8*)&Bsh[off];
            bfl[ni] = *(const f16x8*)&Bsl[off];
        }
#pragma unroll
        for (int mi = 0; mi < 4; ++mi)
#pragma unroll
            for (int ni = 0; ni < 4; ++ni) {
                acc[mi][ni] = __builtin_amdgcn_mfma_f32_16x16x32_f16(afh[mi], bfh[ni], acc[mi][ni], 0, 0, 0);
                acc[mi][ni] = __builtin_amdgcn_mfma_f32_16x16x32_f16(afh[mi], bfl[ni], acc[mi][ni], 0, 0, 0);
                if (SPLIT_A)
                    acc[mi][ni] = __builtin_amdgcn_mfma_f32_16x16x32_f16(afl[mi], bfh[ni], acc[mi][ni], 0, 0, 0);
            }
        __syncthreads();
    }

    long coff = (long)bz * sC;
#pragma unroll
    for (int mi = 0; mi < 4; ++mi) {
#pragma unroll
        for (int ni = 0; ni < 4; ++ni) {
            int n = n0 + wn * 64 + ni * 16 + r16;
            float bv = BIAS ? bias[n] : 0.f;
#pragma unroll
            for (int j = 0; j < 4; ++j) {
                int m = m0 + wm * 64 + mi * 16 + kg * 4 + j;
                float v = acc[mi][ni][j] * DESCL + bv;
                if (EPI == 1) v = fmaxf(v, 0.f);
                if (EPI == 2) v = tanhf(v);
                long idx = coff + (long)m * N + n;
                if (OUTM == 0) {
                    C[idx] = v;
                } else if (OUTM == 1) {
                    float t = v * SCL;
                    _Float16 h = (_Float16)t;
                    Ch[idx] = h;
                    Cl[idx] = (_Float16)(t - (float)h);
                } else {
                    Ch[idx] = (_Float16)(v * SCL);
                }
            }
        }
    }
}

// ---------------------------------------------------------------------------
// K4: GRU recurrence. One block per (dir, batch), 512 threads = 8 waves.
// k-split 2: thread (q,t). Weights register-resident (192 half2 regs).
// h kept f16 in LDS for dots (round-2 proven) + f32 mirror for d output.
// d hi/lo store for step s-1 issued by q==1 waves during step s's dot phase.
__global__ __launch_bounds__(512, 2) void gru_kernel(
    const float* __restrict__ gx_f, const float* __restrict__ gx_b,
    const half2_t* __restrict__ wq_f, const half2_t* __restrict__ wq_b,
    const float* __restrict__ bhh_f, const float* __restrict__ bhh_b,
    _Float16* __restrict__ dh_out, _Float16* __restrict__ dl_out)
{
    int dir = blockIdx.x >> 6;
    int b   = blockIdx.x & 63;
    const float*   gx  = dir ? gx_b : gx_f;
    const half2_t* wq  = dir ? wq_b : wq_f;
    const float*   bhh = dir ? bhh_b : bhh_f;
    int tid = threadIdx.x;
    int t = tid & 255, q = tid >> 8;

    __shared__ __attribute__((aligned(16))) _Float16 hbuf[256];
    __shared__ float hf32[256];
    __shared__ float part[2 * 768];

    half2_t wr[192];
    const half2_t* wbase = wq + (size_t)q * 192 * 256 + t;
#pragma unroll
    for (int m = 0; m < 192; ++m) wr[m] = wbase[m << 8];

    float br = 0.f, bz = 0.f, bn = 0.f, hprev = 0.f;
    if (q == 0) {
        br = bhh[t]; bz = bhh[256 + t]; bn = bhh[512 + t];
        hbuf[t] = (_Float16)0.f;
        hf32[t] = 0.f;
    }
    __syncthreads();

    for (int step = 0; step < Sz; ++step) {
        int s = dir ? (Sz - 1 - step) : step;
        // deferred previous-step d write (overlaps dot phase)
        if (q == 1 && step > 0) {
            int sp = dir ? (Sz - step) : (step - 1);
            float hv = hf32[t] * SCL;
            _Float16 hh = (_Float16)hv;
            size_t idx = (size_t)(b * Sz + sp) * 512 + dir * 256 + t;
            dh_out[idx] = hh;
            dl_out[idx] = (_Float16)(hv - (float)hh);
        }
        const float* g = gx + (size_t)(b * Sz + s) * 768;
        float xr = 0.f, xz = 0.f, xn = 0.f;
        if (q == 0) { xr = g[t]; xz = g[256 + t]; xn = g[512 + t]; }

        float ar = 0.f, az = 0.f, an = 0.f;
        const half4_t* hp = (const half4_t*)hbuf;
#pragma unroll
        for (int jj = 0; jj < 32; ++jj) {
            half4_t hv = hp[q * 32 + jj];
            half2_t h01 = {hv[0], hv[1]};
            half2_t h23 = {hv[2], hv[3]};
            ar = fdot2(wr[jj * 6 + 0], h01, ar); ar = fdot2(wr[jj * 6 + 1], h23, ar);
            az = fdot2(wr[jj * 6 + 2], h01, az); az = fdot2(wr[jj * 6 + 3], h23, az);
            an = fdot2(wr[jj * 6 + 4], h01, an); an = fdot2(wr[jj * 6 + 5], h23, an);
        }
        part[q * 768 + t]       = ar;
        part[q * 768 + 256 + t] = az;
        part[q * 768 + 512 + t] = an;
        __syncthreads();

        if (q == 0) {
            float hr = part[t]       + part[768 + t];
            float hz = part[256 + t] + part[768 + 256 + t];
            float hn = part[512 + t] + part[768 + 512 + t];
            float r  = 1.f / (1.f + expf(-(xr + br + hr)));
            float z  = 1.f / (1.f + expf(-(xz + bz + hz)));
            float nn = tanhf(xn + r * (hn + bn));
            hprev = (1.f - z) * nn + z * hprev;
            hbuf[t] = (_Float16)hprev;
            hf32[t] = hprev;
        }
        __syncthreads();
    }
    // final step's d write
    if (q == 1) {
        int sl = dir ? 0 : (Sz - 1);
        float hv = hf32[t] * SCL;
        _Float16 hh = (_Float16)hv;
        size_t idx = (size_t)(b * Sz + sl) * 512 + dir * 256 + t;
        dh_out[idx] = hh;
        dl_out[idx] = (_Float16)(hv - (float)hh);
    }
}

// ---------------------------------------------------------------------------
// transpose d (hi,lo) [B*S][512] -> dT (hi,lo) [B][512][256]
__global__ __launch_bounds__(256) void dtrans_kernel(
    const _Float16* __restrict__ dh, const _Float16* __restrict__ dl,
    _Float16* __restrict__ dTh, _Float16* __restrict__ dTl)
{
    __shared__ _Float16 th[64][68];
    __shared__ _Float16 tl[64][68];
    int s0 = blockIdx.x << 6;
    int h0 = blockIdx.y << 6;
    int b  = blockIdx.z;
    int tid = threadIdx.x;
#pragma unroll
    for (int i = 0; i < 16; ++i) {
        int idx = tid + i * 256;
        int s = idx >> 6, h = idx & 63;
        size_t gi = (size_t)(b * 256 + s0 + s) * 512 + h0 + h;
        th[s][h] = dh[gi];
        tl[s][h] = dl[gi];
    }
    __syncthreads();
#pragma unroll
    for (int i = 0; i < 16; ++i) {
        int idx = tid + i * 256;
        int h = idx >> 6, s = idx & 63;
        size_t gi = (size_t)(b * 512 + h0 + h) * 256 + s0 + s;
        dTh[gi] = th[s][h];
        dTl[gi] = tl[s][h];
    }
}

// ---------------------------------------------------------------------------
// BN stats over (b, e) for each channel c (layout y[b][CH][256])
__global__ void bn_stats_kernel(const float* __restrict__ y, int CH,
                                float* __restrict__ mean, float* __restrict__ istd)
{
    int c = blockIdx.x, t = threadIdx.x;
    float s = 0.f, ss = 0.f;
    for (int b = 0; b < Bz; ++b) {
        float v = y[((long)b * CH + c) * 256 + t];
        s += v; ss += v * v;
    }
    __shared__ float rs[256], rss[256];
    rs[t] = s; rss[t] = ss; __syncthreads();
    for (int off = 128; off > 0; off >>= 1) {
        if (t < off) { rs[t] += rs[t + off]; rss[t] += rss[t + off]; }
        __syncthreads();
    }
    if (t == 0) {
        float cnt = (float)(Bz * 256);
        float m = rs[0] / cnt;
        float var = rss[0] / cnt - m * m;
        mean[c] = m;
        istd[c] = rsqrtf(var + 1e-5f);
    }
}

// BN apply + activation. HL=1: write scaled hi/lo f16; HL=0: in-place f32.
template<int EPI, int HL>
__global__ void bn_apply_kernel(float* __restrict__ y, _Float16* __restrict__ yh,
                                _Float16* __restrict__ yl, int CH,
                                const float* __restrict__ mean, const float* __restrict__ istd,
                                const float* __restrict__ g, const float* __restrict__ be)
{
    long i = (long)blockIdx.x * 256 + threadIdx.x;
    int c = (int)((i >> 8) % CH);
    float v = (y[i] - mean[c]) * istd[c] * g[c] + be[c];
    v = (EPI == 1) ? fmaxf(v, 0.f) : tanhf(v);
    if (HL) {
        float t = v * SCL;
        _Float16 h = (_Float16)t;
        yh[i] = h;
        yl[i] = (_Float16)(t - (float)h);
    } else {
        y[i] = v;
    }
}

// ---------------------------------------------------------------------------
// Output: cosine similarity * 10
__global__ void out_kernel(const float* __restrict__ e, const float* __restrict__ Vsum,
                           const float* __restrict__ vnorm, float* __restrict__ out)
{
    int bl = blockIdx.x;
    int l = bl & (Lz - 1);
    int t = threadIdx.x;
    float ev = e[(long)bl * 256 + t];
    float vv = Vsum[l * 256 + t];
    __shared__ float rd[256], rn[256];
    rd[t] = ev * vv; rn[t] = ev * ev; __syncthreads();
    for (int off = 128; off > 0; off >>= 1) {
        if (t < off) { rd[t] += rd[t + off]; rn[t] += rn[t + off]; }
        __syncthreads();
    }
    if (t == 0) {
        float num = rd[0];
        float den = fmaxf(sqrtf(rn[0]), 1e-8f) * fmaxf(vnorm[l], 1e-8f);
        out[bl] = num / den * 10.f;
    }
}

// ---------------------------------------------------------------------------
extern "C" void kernel_launch(void* const* d_in, const int* in_sizes, int n_in,
                              void* d_out, int out_size, void* d_ws, size_t ws_size,
                              hipStream_t stream)
{
    const int*   x      = (const int*)d_in[0];
    const int*   V_idx  = (const int*)d_in[1];
    const float* emb    = (const float*)d_in[2];
    const float* w_ih_f = (const float*)d_in[3];
    const float* w_hh_f = (const float*)d_in[4];
    const float* b_ih_f = (const float*)d_in[5];
    const float* b_hh_f = (const float*)d_in[6];
    const float* w_ih_b = (const float*)d_in[7];
    const float* w_hh_b = (const float*)d_in[8];
    const float* b_ih_b = (const float*)d_in[9];
    const float* b_hh_b = (const float*)d_in[10];
    const float* w1     = (const float*)d_in[11];
    const float* b1     = (const float*)d_in[12];
    const float* w2     = (const float*)d_in[13];
    const float* b2     = (const float*)d_in[14];
    const float* g1     = (const float*)d_in[15];
    const float* be1    = (const float*)d_in[16];
    const float* g2     = (const float*)d_in[17];
    const float* be2    = (const float*)d_in[18];

    float* ws = (float*)d_ws;
    float* out = (float*)d_out;

    // ---- workspace layout (float units); total 51,710,976 fl = 207 MB ----
    float*    vsum   = ws;                               // 262144
    float*    vnorm  = ws + 262144;                      // 1024
    float*    mean   = ws + 263168;                      // 1024
    float*    istd   = ws + 264192;                      // 1024
    half2_t*  wqf    = (half2_t*)(ws + 265216);          // 98304
    half2_t*  wqb    = (half2_t*)(ws + 363520);          // 98304
    _Float16* vsh    = (_Float16*)(ws + 461824);         // 131072 fl
    _Float16* vsl    = (_Float16*)(ws + 592896);         // 131072 fl
    _Float16* wihh_f = (_Float16*)(ws + 723968);         // 98304 fl
    _Float16* wihl_f = (_Float16*)(ws + 822272);         // 98304 fl
    _Float16* wihh_b = (_Float16*)(ws + 920576);         // 98304 fl
    _Float16* wihl_b = (_Float16*)(ws + 1018880);        // 98304 fl
    _Float16* w1h    = (_Float16*)(ws + 1117184);        // 65536 fl
    _Float16* w1l    = (_Float16*)(ws + 1182720);        // 65536 fl
    _Float16* w2h    = (_Float16*)(ws + 1248256);        // 65536 fl
    _Float16* w2l    = (_Float16*)(ws + 1313792);        // 65536 fl
    float*    AB     = ws + 1379328;                     // overlay arena
    // arena overlays (liveness-checked):
    _Float16* xeh    = (_Float16*)(AB + 0);              // st1-2
    _Float16* xel    = (_Float16*)(AB + 2097152);
    float*    gxf    = AB + 4194304;                     // st2-3
    float*    gxb    = AB + 16777216;
    _Float16* dh     = (_Float16*)(AB + 29360128);       // st3-4 (+dtrans)
    _Float16* dl     = (_Float16*)(AB + 33554432);
    _Float16* dTh    = (_Float16*)(AB + 0);              // dtrans-st6 (xe/gx dead)
    _Float16* dTl    = (_Float16*)(AB + 4194304);
    float*    d2pre  = AB + 8388608;                     // st4 (gx dead)
    _Float16* d2h    = (_Float16*)(AB + 12582912);       // st4-5
    _Float16* d2l    = (_Float16*)(AB + 14680064);
    _Float16* ah     = (_Float16*)(AB + 16777216);       // st5-6 (gxb/d dead)
    _Float16* al     = (_Float16*)(AB + 25165824);
    _Float16* c16    = (_Float16*)(AB + 33554432);       // st6-7 (dl dead)
    float*    epre   = AB + 0;                           // st7-8 (dT/d2 dead)

    // Stage 1: gathers + packs
    vsum_kernel<<<Lz, 256, 0, stream>>>(V_idx, emb, vsum, vsh, vsl, vnorm);
    xe_kernel<<<Bz * Sz, 256, 0, stream>>>(x, emb, xeh, xel);
    wpack_kernel<<<384, 256, 0, stream>>>(w_hh_f, w_hh_b, wqf, wqb);
    cvtsplit_kernel<<<768, 256, 0, stream>>>(w_ih_f, wihh_f, wihl_f, 196608);
    cvtsplit_kernel<<<768, 256, 0, stream>>>(w_ih_b, wihh_b, wihl_b, 196608);
    cvtsplit_kernel<<<512, 256, 0, stream>>>(w1, w1h, w1l, 131072);
    cvtsplit_kernel<<<512, 256, 0, stream>>>(w2, w2h, w2l, 131072);

    // Stage 2: gx = xe @ w_ih^T + b_ih  (M=16384, N=768, K=256), f32 out
    gemm_mfma<0, 1, 0, 1><<<dim3(6, 128, 1), 256, 0, stream>>>(
        xeh, xel, wihh_f, wihl_f, b_ih_f, gxf, nullptr, nullptr, Bz * Sz, 768, Ez, 0, 0, 0);
    gemm_mfma<0, 1, 0, 1><<<dim3(6, 128, 1), 256, 0, stream>>>(
        xeh, xel, wihh_b, wihl_b, b_ih_b, gxb, nullptr, nullptr, Bz * Sz, 768, Ez, 0, 0, 0);

    // Stage 3: GRU recurrence -> d hi/lo [B,S,512]; transpose -> dT [B,512,256]
    gru_kernel<<<128, 512, 0, stream>>>(gxf, gxb, wqf, wqb, b_hh_f, b_hh_b, dh, dl);
    dtrans_kernel<<<dim3(4, 8, Bz), 256, 0, stream>>>(dh, dl, dTh, dTl);

    // Stage 4: d2pre = d @ w1^T + b1 (M=16384, N=256, K=512) f32; BN1+relu -> hi/lo
    gemm_mfma<0, 1, 0, 1><<<dim3(2, 128, 1), 256, 0, stream>>>(
        dh, dl, w1h, w1l, b1, d2pre, nullptr, nullptr, Bz * Sz, Ez, 512, 0, 0, 0);
    bn_stats_kernel<<<Sz, 256, 0, stream>>>(d2pre, Sz, mean, istd);
    bn_apply_kernel<1, 1><<<Bz * Sz, 256, 0, stream>>>(d2pre, d2h, d2l, Sz, mean, istd, g1, be1);

    // Stage 5: a[b] = tanh(Vsum @ d2[b]^T)  (M=1024, N=256, K=256) -> hi/lo
    gemm_mfma<2, 0, 1, 1><<<dim3(2, 8, Bz), 256, 0, stream>>>(
        vsh, vsl, d2h, d2l, nullptr, nullptr, ah, al, Lz, Sz, Ez, 0, (long)Sz * Ez, (long)Lz * Sz);

    // Stage 6: c[b] = relu(a[b] @ dT[b]^T)  (M=1024, N=512, K=256) -> hi only
    gemm_mfma<1, 0, 2, 1><<<dim3(4, 8, Bz), 256, 0, stream>>>(
        ah, al, dTh, dTl, nullptr, nullptr, c16, nullptr, Lz, 512, Sz,
        (long)Lz * Sz, (long)512 * Sz, (long)Lz * 512);

    // Stage 7: epre = c @ w2^T + b2 (M=65536, N=256, K=512, A hi-only) f32; BN2+tanh
    gemm_mfma<0, 1, 0, 0><<<dim3(2, 512, 1), 256, 0, stream>>>(
        c16, nullptr, w2h, w2l, b2, epre, nullptr, nullptr, Bz * Lz, Ez, 512, 0, 0, 0);
    bn_stats_kernel<<<Lz, 256, 0, stream>>>(epre, Lz, mean, istd);
    bn_apply_kernel<2, 0><<<Bz * Lz, 256, 0, stream>>>(epre, nullptr, nullptr, Lz, mean, istd, g2, be2);

    // Stage 8: output
    out_kernel<<<Bz * Lz, 256, 0, stream>>>(epre, vsum, vnorm, out);
}